// Round 1
// baseline (1303.633 us; speedup 1.0000x reference)
//
#include <hip/hip_runtime.h>

// CubePadding: x [6,128,512,512] f32, p=1 -> out [6,128,514,514] f32
// Face order: back(0), down(1), front(2), left(3), right(4), top(5)

#define NC      128
#define HH      512
#define WW      512
#define HP      514                  // H + 2p, p = 1
#define FACE_IN  (HH * WW)           // 262144 = 2^18
#define FACE_OUT (HP * HP)           // 264196
#define PER_FC   (2 * HP + 2 * HH)   // 2052 border elements per (face,channel)

// ---------------------------------------------------------------------------
// Interior: out[f,c,h+1,w+1] = x[f,c,h,w]. float4 loads (aligned), scalar
// coalesced stores (output row start is not 16B-aligned).
// ---------------------------------------------------------------------------
__global__ void cube_interior_kernel(const float* __restrict__ x,
                                     float* __restrict__ out) {
    unsigned tid  = blockIdx.x * blockDim.x + threadIdx.x;
    unsigned idx4 = tid * 4u;
    const unsigned total = 6u * NC * FACE_IN;  // 201,326,592
    if (idx4 >= total) return;

    unsigned fc  = idx4 >> 18;                 // / FACE_IN
    unsigned rem = idx4 & (FACE_IN - 1);
    unsigned h   = rem >> 9;                   // / WW
    unsigned w   = rem & (WW - 1);

    const float4 v = *reinterpret_cast<const float4*>(x + idx4);
    float* o = out + (size_t)fc * FACE_OUT + (size_t)(h + 1) * HP + (w + 1);
    o[0] = v.x; o[1] = v.y; o[2] = v.z; o[3] = v.w;
}

// ---------------------------------------------------------------------------
// Border: one thread per halo element. Derived from the reference:
//   t (top strip, k in [0,W)):
//     f0: ft[0][W-1-k]   f1: ff[H-1][k]      f2: ft[H-1][k]
//     f3: ft[k][0]       f4: ft[H-1-k][W-1]  f5: fb[0][W-1-k]
//   d (down strip):
//     f0: fd[H-1][W-1-k] f1: fb[H-1][W-1-k]  f2: fd[0][k]
//     f3: fd[H-1-k][0]   f4: fd[k][W-1]      f5: ff[0][k]
//   l (left col, k = row):
//     f0: fr[k][W-1]     f1: fl[H-1][W-1-k]  f2: fl[k][W-1]
//     f3: fb[k][W-1]     f4: ff[k][W-1]      f5: fl[0][k]
//   r (right col):
//     f0: fl[k][0]       f1: fr[H-1][k]      f2: fr[k][0]
//     f3: ff[k][0]       f4: fb[k][0]        f5: fr[0][W-1-k]
//   corners = clamp of the t/d strip column index (reference tiles the strip
//   endpoint), i.e. k = clamp(j-1, 0, W-1) on the top/bottom full-width rows.
// ---------------------------------------------------------------------------
__global__ void cube_border_kernel(const float* __restrict__ x,
                                   float* __restrict__ out) {
    int tid = blockIdx.x * blockDim.x + threadIdx.x;
    const int total = 6 * NC * PER_FC;
    if (tid >= total) return;

    int fc = tid / PER_FC;
    int e  = tid - fc * PER_FC;
    int f  = fc >> 7;          // / NC
    int c  = fc & (NC - 1);

    const size_t ch = (size_t)c * FACE_IN;
    const float* fb_ = x + 0 * (size_t)NC * FACE_IN + ch;
    const float* fd_ = x + 1 * (size_t)NC * FACE_IN + ch;
    const float* ff_ = x + 2 * (size_t)NC * FACE_IN + ch;
    const float* fl_ = x + 3 * (size_t)NC * FACE_IN + ch;
    const float* fr_ = x + 4 * (size_t)NC * FACE_IN + ch;
    const float* ft_ = x + 5 * (size_t)NC * FACE_IN + ch;

    float val;
    int oi, oj;

    if (e < HP) {
        // top row (includes corners via clamp)
        oi = 0; oj = e;
        int k = min(max(oj - 1, 0), WW - 1);
        switch (f) {
            case 0:  val = ft_[(WW - 1) - k];                 break;
            case 1:  val = ff_[(HH - 1) * WW + k];            break;
            case 2:  val = ft_[(HH - 1) * WW + k];            break;
            case 3:  val = ft_[k * WW];                       break;
            case 4:  val = ft_[(HH - 1 - k) * WW + (WW - 1)]; break;
            default: val = fb_[(WW - 1) - k];                 break;
        }
    } else if (e < 2 * HP) {
        // bottom row (includes corners via clamp)
        oi = HP - 1; oj = e - HP;
        int k = min(max(oj - 1, 0), WW - 1);
        switch (f) {
            case 0:  val = fd_[(HH - 1) * WW + (WW - 1) - k]; break;
            case 1:  val = fb_[(HH - 1) * WW + (WW - 1) - k]; break;
            case 2:  val = fd_[k];                            break;
            case 3:  val = fd_[(HH - 1 - k) * WW];            break;
            case 4:  val = fd_[k * WW + (WW - 1)];            break;
            default: val = ff_[k];                            break;
        }
    } else if (e < 2 * HP + HH) {
        // left column, output rows 1..H
        int k = e - 2 * HP;
        oi = k + 1; oj = 0;
        switch (f) {
            case 0:  val = fr_[k * WW + (WW - 1)];            break;
            case 1:  val = fl_[(HH - 1) * WW + (WW - 1) - k]; break;
            case 2:  val = fl_[k * WW + (WW - 1)];            break;
            case 3:  val = fb_[k * WW + (WW - 1)];            break;
            case 4:  val = ff_[k * WW + (WW - 1)];            break;
            default: val = fl_[k];                            break;
        }
    } else {
        // right column, output rows 1..H
        int k = e - (2 * HP + HH);
        oi = k + 1; oj = HP - 1;
        switch (f) {
            case 0:  val = fl_[k * WW];                       break;
            case 1:  val = fr_[(HH - 1) * WW + k];            break;
            case 2:  val = fr_[k * WW];                       break;
            case 3:  val = ff_[k * WW];                       break;
            case 4:  val = fb_[k * WW];                       break;
            default: val = fr_[(WW - 1) - k];                 break;
        }
    }

    out[(size_t)fc * FACE_OUT + (size_t)oi * HP + oj] = val;
}

extern "C" void kernel_launch(void* const* d_in, const int* in_sizes, int n_in,
                              void* d_out, int out_size, void* d_ws, size_t ws_size,
                              hipStream_t stream) {
    const float* x = (const float*)d_in[0];
    float* out = (float*)d_out;

    // Interior copy: 6*128*512*512 / 4 threads
    {
        unsigned total4 = 6u * NC * FACE_IN / 4u;  // 50,331,648
        dim3 block(256);
        dim3 grid((total4 + 255u) / 256u);
        cube_interior_kernel<<<grid, block, 0, stream>>>(x, out);
    }
    // Halo fill: 6*128*2052 threads
    {
        int total = 6 * NC * PER_FC;               // 1,575,936
        dim3 block(256);
        dim3 grid((total + 255) / 256);
        cube_border_kernel<<<grid, block, 0, stream>>>(x, out);
    }
}